// Round 1
// baseline (500.967 us; speedup 1.0000x reference)
//
#include <hip/hip_runtime.h>
#include <stdint.h>

#define BDIM 64
#define TDIM 512
#define FDIM 1024
#define NTOT 33554432.0f   // 64*512*1024
#define EPS  1e-5f

typedef unsigned short ushort_t;
typedef unsigned short ushort4_t __attribute__((ext_vector_type(4)));
typedef short short8 __attribute__((ext_vector_type(8)));
typedef float floatx4 __attribute__((ext_vector_type(4)));

__device__ __forceinline__ ushort_t f2bf(float f) {
    union { float f; uint32_t u; } v; v.f = f;
    uint32_t r = (v.u + 0x7fffu + ((v.u >> 16) & 1u)) >> 16;
    return (ushort_t)r;
}

// async global->LDS, 16B per lane; LDS dest is wave-uniform base + lane*16
__device__ __forceinline__ void async16(const ushort_t* g, ushort_t* l) {
    __builtin_amdgcn_global_load_lds(
        (const __attribute__((address_space(1))) void*)g,
        (__attribute__((address_space(3))) void*)l, 16, 0, 0);
}

// ---------------------------------------------------------------------------
// Kernel 1: single pass over x: accumulate sum/sumsq (for batchnorm stats)
// and write xT_bf16[b][f][t] (transposed, bf16) for the GEMM B operand.
// Tile 64(t) x 64(f) per block. grid = 64 * 8 * 16 = 8192 blocks.
// ---------------------------------------------------------------------------
__global__ __launch_bounds__(256) void k_stats_transpose(
    const float* __restrict__ x, ushort_t* __restrict__ xT,
    float* __restrict__ stats)
{
    __shared__ ushort_t tile[64 * 68];   // [f_local][t_local], stride 68 (8B-aligned rows, odd word stride)
    __shared__ float red[8];

    int tid = threadIdx.x;
    int bid = blockIdx.x;
    int b   = bid >> 7;
    int rem = bid & 127;
    int t0  = (rem >> 4) << 6;
    int f0  = (rem & 15) << 6;

    int r16 = tid >> 4, c4 = tid & 15;
    float s = 0.f, q = 0.f;
    const float* xb = x + ((size_t)(b * TDIM + t0) * FDIM) + f0;

#pragma unroll
    for (int p = 0; p < 4; ++p) {
        int row = p * 16 + r16;
        float4 v = *(const float4*)(xb + (size_t)row * FDIM + c4 * 4);
        s += v.x + v.y + v.z + v.w;
        q += v.x * v.x + v.y * v.y + v.z * v.z + v.w * v.w;
        int fl = c4 * 4;
        tile[(fl + 0) * 68 + row] = f2bf(v.x);
        tile[(fl + 1) * 68 + row] = f2bf(v.y);
        tile[(fl + 2) * 68 + row] = f2bf(v.z);
        tile[(fl + 3) * 68 + row] = f2bf(v.w);
    }

    // wave (64-lane) reduction, then block reduction, one atomic pair per block
#pragma unroll
    for (int off = 32; off > 0; off >>= 1) {
        s += __shfl_down(s, off, 64);
        q += __shfl_down(q, off, 64);
    }
    int lane = tid & 63, w = tid >> 6;
    if (lane == 0) { red[w] = s; red[4 + w] = q; }
    __syncthreads();
    if (tid == 0) {
        atomicAdd(&stats[0], red[0] + red[1] + red[2] + red[3]);
        atomicAdd(&stats[1], red[4] + red[5] + red[6] + red[7]);
    }

    // phase 2: coalesced write of transposed bf16 tile
    int fr = tid >> 2, cb = (tid & 3) * 16;
    ushort_t* dst = xT + ((size_t)(b * FDIM + f0 + fr) * TDIM) + t0 + cb;
    const ushort_t* srcrow = &tile[fr * 68 + cb];
#pragma unroll
    for (int k = 0; k < 4; ++k) {
        *(ushort4_t*)(dst + k * 4) = *(const ushort4_t*)(srcrow + k * 4);
    }
}

// ---------------------------------------------------------------------------
// Kernel 2: cast W to bf16, compute per-row d[u] = c*rowsumW[u] + bias[u]
// where c = beta - mean*a (stats already final — stream-ordered after k1).
// One block per row u (512 blocks).
// ---------------------------------------------------------------------------
__global__ __launch_bounds__(256) void k_wprep(
    const float* __restrict__ W, const float* __restrict__ bias,
    const float* __restrict__ gamma, const float* __restrict__ beta,
    const float* __restrict__ stats,
    ushort_t* __restrict__ Wb, float* __restrict__ d)
{
    __shared__ float red[4];
    int u = blockIdx.x, tid = threadIdx.x;
    const float* row = W + (size_t)u * 512;
    float v0 = row[tid], v1 = row[tid + 256];
    Wb[u * 512 + tid]       = f2bf(v0);
    Wb[u * 512 + tid + 256] = f2bf(v1);
    float s = v0 + v1;
#pragma unroll
    for (int off = 32; off > 0; off >>= 1) s += __shfl_down(s, off, 64);
    int lane = tid & 63, w = tid >> 6;
    if (lane == 0) red[w] = s;
    __syncthreads();
    if (tid == 0) {
        float rowsum = red[0] + red[1] + red[2] + red[3];
        float mean = stats[0] * (1.f / NTOT);
        float var  = stats[1] * (1.f / NTOT) - mean * mean;
        float a    = gamma[0] * rsqrtf(var + EPS);
        float c    = beta[0] - mean * a;
        d[u] = c * rowsum + bias[u];
    }
}

// ---------------------------------------------------------------------------
// Kernel 3: GEMM C[t,f] = sum_k Wb[t,k] * xT[b,f,k]  (gemm_bt, m97 structure)
// 128x128 tile, BK=32, 4 waves (2x2), 16x16x32 bf16 MFMA, 4x4 frags/wave.
// LDS chunk layout: chunk(q, m) at (q*128+m)*16B  -> fragment ds_read_b128
// has only 2-way bank aliasing (free), and global_load_lds fills it linearly.
// Epilogue: h = a*acc + d[t]; out = x + relu(h).
// ---------------------------------------------------------------------------
__global__ __launch_bounds__(256) void k_gemm(
    const ushort_t* __restrict__ Wb, const ushort_t* __restrict__ xT,
    const float* __restrict__ x, const float* __restrict__ d,
    const float* __restrict__ stats, const float* __restrict__ gamma,
    float* __restrict__ out)
{
    __shared__ ushort_t ldsA[4096];  // 8KB: chunks (q*128 + m)*8 ushorts
    __shared__ ushort_t ldsB[4096];

    int tid = threadIdx.x;
    int w = tid >> 6, lane = tid & 63;
    int mt = blockIdx.x;             // 0..3   (t tile)
    int nt = blockIdx.y;             // 0..511 (b, f tile)
    int b = nt >> 3, ft = nt & 7;
    int wr = w >> 1, wc = w & 1;
    int l15 = lane & 15, q = lane >> 4;

    const ushort_t* Abase = Wb + (size_t)(mt * 128) * 512;
    const ushort_t* Bbase = xT + ((size_t)b * FDIM + ft * 128) * 512;

    floatx4 acc[4][4] = {};

    for (int kt = 0; kt < 512; kt += 32) {
        // stage A (8KB) and B (8KB): 2 calls each, 256 lanes x 16B per call
#pragma unroll
        for (int c = 0; c < 2; ++c) {
            int ci = c * 256 + tid;        // chunk id = q*128 + m
            int qs = ci >> 7, is = ci & 127;
            async16(Abase + (size_t)is * 512 + kt + qs * 8, &ldsA[ci * 8]);
            async16(Bbase + (size_t)is * 512 + kt + qs * 8, &ldsB[ci * 8]);
        }
        __syncthreads();   // drains vmcnt before any ds_read

        short8 af[4], bfr[4];
#pragma unroll
        for (int i = 0; i < 4; ++i) {
            int m = wr * 64 + i * 16 + l15;
            af[i] = *(const short8*)&ldsA[(q * 128 + m) * 8];
        }
#pragma unroll
        for (int j = 0; j < 4; ++j) {
            int n = wc * 64 + j * 16 + l15;
            bfr[j] = *(const short8*)&ldsB[(q * 128 + n) * 8];
        }
#pragma unroll
        for (int i = 0; i < 4; ++i)
#pragma unroll
            for (int j = 0; j < 4; ++j)
                acc[i][j] = __builtin_amdgcn_mfma_f32_16x16x32_bf16(
                    af[i], bfr[j], acc[i][j], 0, 0, 0);
        __syncthreads();   // before next tile overwrites LDS
    }

    // epilogue: scalar BN folded in
    float mean = stats[0] * (1.f / NTOT);
    float var  = stats[1] * (1.f / NTOT) - mean * mean;
    float a    = gamma[0] * rsqrtf(var + EPS);

#pragma unroll
    for (int i = 0; i < 4; ++i) {
#pragma unroll
        for (int r = 0; r < 4; ++r) {
            int t = mt * 128 + wr * 64 + i * 16 + q * 4 + r;
            float dt = d[t];
            size_t rowbase = ((size_t)b * TDIM + t) * FDIM + ft * 128 + wc * 64 + l15;
#pragma unroll
            for (int j = 0; j < 4; ++j) {
                size_t idx = rowbase + j * 16;
                float h = a * acc[i][j][r] + dt;
                out[idx] = x[idx] + fmaxf(h, 0.f);
            }
        }
    }
}

// ---------------------------------------------------------------------------
extern "C" void kernel_launch(void* const* d_in, const int* in_sizes, int n_in,
                              void* d_out, int out_size, void* d_ws, size_t ws_size,
                              hipStream_t stream) {
    const float* x     = (const float*)d_in[0];
    const float* W     = (const float*)d_in[1];
    const float* bias  = (const float*)d_in[2];
    const float* gamma = (const float*)d_in[3];
    const float* beta  = (const float*)d_in[4];
    float* out = (float*)d_out;

    char* ws = (char*)d_ws;
    float*    stats = (float*)ws;                 // 8 B   (zeroed below)
    float*    dvec  = (float*)(ws + 1024);        // 2 KB
    ushort_t* Wb    = (ushort_t*)(ws + 4096);     // 512 KB
    ushort_t* xT    = (ushort_t*)(ws + (1 << 20)); // 64 MB

    hipMemsetAsync(stats, 0, 2 * sizeof(float), stream);
    k_stats_transpose<<<8192, 256, 0, stream>>>(x, xT, stats);
    k_wprep<<<512, 256, 0, stream>>>(W, bias, gamma, beta, stats, Wb, dvec);
    k_gemm<<<dim3(4, 512), 256, 0, stream>>>(Wb, xT, x, dvec, stats, gamma, out);
}

// Round 2
// 343.624 us; speedup vs baseline: 1.4579x; 1.4579x over previous
//
#include <hip/hip_runtime.h>
#include <stdint.h>

#define TDIM 512
#define FDIM 1024
#define NTOT 33554432.0f   // 64*512*1024
#define EPS  1e-5f

typedef unsigned short ushort_t;
typedef unsigned short ushort4_t __attribute__((ext_vector_type(4)));
typedef short short8 __attribute__((ext_vector_type(8)));
typedef float floatx4 __attribute__((ext_vector_type(4)));

__device__ __forceinline__ ushort_t f2bf(float f) {
    union { float f; uint32_t u; } v; v.f = f;
    uint32_t r = (v.u + 0x7fffu + ((v.u >> 16) & 1u)) >> 16;
    return (ushort_t)r;
}

// async global->LDS, 16B per lane; LDS dest is wave-uniform base + lane*16
__device__ __forceinline__ void async16(const ushort_t* g, ushort_t* l) {
    __builtin_amdgcn_global_load_lds(
        (const __attribute__((address_space(1))) void*)g,
        (__attribute__((address_space(3))) void*)l, 16, 0, 0);
}

// ---------------------------------------------------------------------------
// Kernel 1: one pass over x: per-block partial sum/sumsq (NO atomics) and
// write xT_bf16[b][f][t]. Tile 64(t) x 128(f). grid = 64*8*8 = 4096 blocks.
// 8 float4 loads hoisted into registers for MLP (8KB in flight per wave).
// ---------------------------------------------------------------------------
__global__ __launch_bounds__(256) void k_stats_transpose(
    const float* __restrict__ x, ushort_t* __restrict__ xT,
    float2* __restrict__ partials)
{
    __shared__ ushort_t tile[128 * 68];   // [f_local][t_local], 17KB
    __shared__ float red[8];

    int tid = threadIdx.x;
    int bid = blockIdx.x;
    int b   = bid >> 6;
    int t0  = ((bid >> 3) & 7) << 6;
    int f0  = (bid & 7) << 7;

    int r8 = tid >> 5, c8 = tid & 31;     // wave: 2 rows x 512B contiguous
    const float* xb = x + ((size_t)(b * TDIM + t0) * FDIM) + f0;

    float4 v[8];
#pragma unroll
    for (int p = 0; p < 8; ++p)
        v[p] = *(const float4*)(xb + (size_t)(p * 8 + r8) * FDIM + c8 * 4);

    float s = 0.f, q = 0.f;
#pragma unroll
    for (int p = 0; p < 8; ++p) {
        float4 t = v[p];
        s += t.x + t.y + t.z + t.w;
        q += t.x * t.x + t.y * t.y + t.z * t.z + t.w * t.w;
        int row = p * 8 + r8;
        int fl  = c8 * 4;
        tile[(fl + 0) * 68 + row] = f2bf(t.x);
        tile[(fl + 1) * 68 + row] = f2bf(t.y);
        tile[(fl + 2) * 68 + row] = f2bf(t.z);
        tile[(fl + 3) * 68 + row] = f2bf(t.w);
    }

#pragma unroll
    for (int off = 32; off > 0; off >>= 1) {
        s += __shfl_down(s, off, 64);
        q += __shfl_down(q, off, 64);
    }
    int lane = tid & 63, w = tid >> 6;
    if (lane == 0) { red[w] = s; red[4 + w] = q; }
    __syncthreads();   // covers tile writes AND red[]
    if (tid == 0) {
        partials[bid] = make_float2(red[0] + red[1] + red[2] + red[3],
                                    red[4] + red[5] + red[6] + red[7]);
    }

    // phase 2: write transposed bf16 tile; thread = half a row (32 ushorts)
    int fr = tid >> 1, half = tid & 1;
    ushort_t* dst = xT + ((size_t)(b * FDIM + f0 + fr) * TDIM) + t0 + half * 32;
    const ushort_t* srcp = &tile[fr * 68 + half * 32];
#pragma unroll
    for (int k = 0; k < 8; ++k)
        *(ushort4_t*)(dst + k * 4) = *(const ushort4_t*)(srcp + k * 4);
}

// ---------------------------------------------------------------------------
// Kernel 2: cast W to bf16 + per-row sum (stats-independent; runs anytime).
// ---------------------------------------------------------------------------
__global__ __launch_bounds__(256) void k_wcast(
    const float* __restrict__ W, ushort_t* __restrict__ Wb,
    float* __restrict__ rowsumW)
{
    __shared__ float red[4];
    int u = blockIdx.x, tid = threadIdx.x;
    const float* row = W + (size_t)u * 512;
    float v0 = row[tid], v1 = row[tid + 256];
    Wb[u * 512 + tid]       = f2bf(v0);
    Wb[u * 512 + tid + 256] = f2bf(v1);
    float s = v0 + v1;
#pragma unroll
    for (int off = 32; off > 0; off >>= 1) s += __shfl_down(s, off, 64);
    int lane = tid & 63, w = tid >> 6;
    if (lane == 0) red[w] = s;
    __syncthreads();
    if (tid == 0) rowsumW[u] = red[0] + red[1] + red[2] + red[3];
}

// ---------------------------------------------------------------------------
// Kernel 3: single-block final reduce: partials -> (a, c); d[u] = c*rowsumW+b.
// ---------------------------------------------------------------------------
__global__ __launch_bounds__(256) void k_reduce(
    const float2* __restrict__ partials, const float* __restrict__ rowsumW,
    const float* __restrict__ bias, const float* __restrict__ gamma,
    const float* __restrict__ beta, float* __restrict__ stats,
    float* __restrict__ d)
{
    __shared__ float red[8];
    __shared__ float sac[2];
    int tid = threadIdx.x;
    float s = 0.f, q = 0.f;
#pragma unroll
    for (int i = 0; i < 16; ++i) {
        float2 p = partials[i * 256 + tid];
        s += p.x; q += p.y;
    }
#pragma unroll
    for (int off = 32; off > 0; off >>= 1) {
        s += __shfl_down(s, off, 64);
        q += __shfl_down(q, off, 64);
    }
    int lane = tid & 63, w = tid >> 6;
    if (lane == 0) { red[w] = s; red[4 + w] = q; }
    __syncthreads();
    if (tid == 0) {
        float S = red[0] + red[1] + red[2] + red[3];
        float Q = red[4] + red[5] + red[6] + red[7];
        float mean = S * (1.f / NTOT);
        float var  = Q * (1.f / NTOT) - mean * mean;
        float a    = gamma[0] * rsqrtf(var + EPS);
        float c    = beta[0] - mean * a;
        stats[0] = a;
        sac[0] = a; sac[1] = c;
    }
    __syncthreads();
    float c = sac[1];
    d[tid]       = c * rowsumW[tid]       + bias[tid];
    d[tid + 256] = c * rowsumW[tid + 256] + bias[tid + 256];
}

// ---------------------------------------------------------------------------
// Kernel 4: GEMM C[t,f] = sum_k Wb[t,k] * xT[b,f,k]  (gemm_bt, m97 structure)
// 128x128 tile, BK=32, 4 waves (2x2), 16x16x32 bf16 MFMA, 4x4 frags/wave.
// Epilogue: h = a*acc + d[t]; out = x + relu(h).
// ---------------------------------------------------------------------------
__global__ __launch_bounds__(256) void k_gemm(
    const ushort_t* __restrict__ Wb, const ushort_t* __restrict__ xT,
    const float* __restrict__ x, const float* __restrict__ d,
    const float* __restrict__ stats, float* __restrict__ out)
{
    __shared__ ushort_t ldsA[4096];  // 8KB: chunks (q*128 + m)*8 ushorts
    __shared__ ushort_t ldsB[4096];

    int tid = threadIdx.x;
    int w = tid >> 6, lane = tid & 63;
    int mt = blockIdx.x;             // 0..3   (t tile)
    int nt = blockIdx.y;             // 0..511 (b, f tile)
    int b = nt >> 3, ft = nt & 7;
    int wr = w >> 1, wc = w & 1;
    int l15 = lane & 15, q = lane >> 4;

    const ushort_t* Abase = Wb + (size_t)(mt * 128) * 512;
    const ushort_t* Bbase = xT + ((size_t)b * FDIM + ft * 128) * 512;

    floatx4 acc[4][4] = {};

    for (int kt = 0; kt < 512; kt += 32) {
#pragma unroll
        for (int c = 0; c < 2; ++c) {
            int ci = c * 256 + tid;        // chunk id = q*128 + m
            int qs = ci >> 7, is = ci & 127;
            async16(Abase + (size_t)is * 512 + kt + qs * 8, &ldsA[ci * 8]);
            async16(Bbase + (size_t)is * 512 + kt + qs * 8, &ldsB[ci * 8]);
        }
        __syncthreads();

        short8 af[4], bfr[4];
#pragma unroll
        for (int i = 0; i < 4; ++i) {
            int m = wr * 64 + i * 16 + l15;
            af[i] = *(const short8*)&ldsA[(q * 128 + m) * 8];
        }
#pragma unroll
        for (int j = 0; j < 4; ++j) {
            int n = wc * 64 + j * 16 + l15;
            bfr[j] = *(const short8*)&ldsB[(q * 128 + n) * 8];
        }
#pragma unroll
        for (int i = 0; i < 4; ++i)
#pragma unroll
            for (int j = 0; j < 4; ++j)
                acc[i][j] = __builtin_amdgcn_mfma_f32_16x16x32_bf16(
                    af[i], bfr[j], acc[i][j], 0, 0, 0);
        __syncthreads();
    }

    float a = stats[0];
#pragma unroll
    for (int i = 0; i < 4; ++i) {
#pragma unroll
        for (int r = 0; r < 4; ++r) {
            int t = mt * 128 + wr * 64 + i * 16 + q * 4 + r;
            float dt = d[t];
            size_t rowbase = ((size_t)b * TDIM + t) * FDIM + ft * 128 + wc * 64 + l15;
#pragma unroll
            for (int j = 0; j < 4; ++j) {
                size_t idx = rowbase + j * 16;
                float h = a * acc[i][j][r] + dt;
                out[idx] = x[idx] + fmaxf(h, 0.f);
            }
        }
    }
}

// ---------------------------------------------------------------------------
extern "C" void kernel_launch(void* const* d_in, const int* in_sizes, int n_in,
                              void* d_out, int out_size, void* d_ws, size_t ws_size,
                              hipStream_t stream) {
    const float* x     = (const float*)d_in[0];
    const float* W     = (const float*)d_in[1];
    const float* bias  = (const float*)d_in[2];
    const float* gamma = (const float*)d_in[3];
    const float* beta  = (const float*)d_in[4];
    float* out = (float*)d_out;

    char* ws = (char*)d_ws;
    float*    stats    = (float*)ws;                  // 8 B
    float*    dvec     = (float*)(ws + 1024);         // 2 KB
    float*    rowsumW  = (float*)(ws + 4096);         // 2 KB
    float2*   partials = (float2*)(ws + 8192);        // 32 KB
    ushort_t* Wb       = (ushort_t*)(ws + (64 << 10)); // 512 KB
    ushort_t* xT       = (ushort_t*)(ws + (1 << 20));  // 64 MB

    k_stats_transpose<<<4096, 256, 0, stream>>>(x, xT, partials);
    k_wcast<<<512, 256, 0, stream>>>(W, Wb, rowsumW);
    k_reduce<<<1, 256, 0, stream>>>(partials, rowsumW, bias, gamma, beta, stats, dvec);
    k_gemm<<<dim3(4, 512), 256, 0, stream>>>(Wb, xT, x, dvec, stats, out);
}

// Round 3
// 327.711 us; speedup vs baseline: 1.5287x; 1.0486x over previous
//
#include <hip/hip_runtime.h>
#include <stdint.h>

#define TDIM 512
#define FDIM 1024
#define NTOT 33554432.0f   // 64*512*1024
#define EPS  1e-5f

typedef unsigned short ushort_t;
typedef unsigned short ushort4_t __attribute__((ext_vector_type(4)));
typedef short short8 __attribute__((ext_vector_type(8)));
typedef float floatx4 __attribute__((ext_vector_type(4)));

__device__ __forceinline__ ushort_t f2bf(float f) {
    union { float f; uint32_t u; } v; v.f = f;
    uint32_t r = (v.u + 0x7fffu + ((v.u >> 16) & 1u)) >> 16;
    return (ushort_t)r;
}

// async global->LDS, 16B per lane; LDS dest is wave-uniform base + lane*16
__device__ __forceinline__ void async16(const ushort_t* g, ushort_t* l) {
    __builtin_amdgcn_global_load_lds(
        (const __attribute__((address_space(1))) void*)g,
        (__attribute__((address_space(3))) void*)l, 16, 0, 0);
}

// Chunked tile layout (the GEMM's exact LDS image, 8KB per (tile, kt)):
//   tile(b,ft,kt) base = ((b*8+ft)*16 + kt) * 4096 ushorts
//   element (k,n): offset (q*128 + n)*8 + e,  q=(k&31)>>3, e=k&7, n=col&127

// ---------------------------------------------------------------------------
// Kernel 1: pass over x: per-block partial sum/sumsq (no atomics) + write
// xT in CHUNKED bf16 layout. Tile 64(t) x 128(f). grid = 4096 blocks.
// ---------------------------------------------------------------------------
__global__ __launch_bounds__(256) void k_stats_transpose(
    const float* __restrict__ x, ushort_t* __restrict__ xTC,
    float2* __restrict__ partials)
{
    __shared__ ushort_t tile[64 * 128];   // [t][f], 16KB
    __shared__ float red[8];

    int tid = threadIdx.x, bid = blockIdx.x;
    int b  = bid >> 6;
    int t0 = ((bid >> 3) & 7) << 6;
    int ft = bid & 7;
    int f0 = ft << 7;

    int r8 = tid >> 5, c8 = tid & 31;
    const float* xb = x + ((size_t)(b * TDIM + t0) * FDIM) + f0;

    float4 v[8];
#pragma unroll
    for (int p = 0; p < 8; ++p)
        v[p] = *(const float4*)(xb + (size_t)(p * 8 + r8) * FDIM + c8 * 4);

    float s = 0.f, q = 0.f;
#pragma unroll
    for (int p = 0; p < 8; ++p) {
        float4 t = v[p];
        s += t.x + t.y + t.z + t.w;
        q += t.x * t.x + t.y * t.y + t.z * t.z + t.w * t.w;
        ushort4_t pk;
        pk[0] = f2bf(t.x); pk[1] = f2bf(t.y); pk[2] = f2bf(t.z); pk[3] = f2bf(t.w);
        *(ushort4_t*)&tile[(p * 8 + r8) * 128 + c8 * 4] = pk;   // b64, conflict-free
    }

#pragma unroll
    for (int off = 32; off > 0; off >>= 1) {
        s += __shfl_down(s, off, 64);
        q += __shfl_down(q, off, 64);
    }
    int lane = tid & 63, w = tid >> 6;
    if (lane == 0) { red[w] = s; red[4 + w] = q; }
    __syncthreads();   // covers tile writes AND red[]
    if (tid == 0) {
        partials[bid] = make_float2(red[0] + red[1] + red[2] + red[3],
                                    red[4] + red[5] + red[6] + red[7]);
    }

    // phase 2: gather-transpose to chunked layout; stores are lane-contiguous
    // 16B -> 1KB/wave coalesced. LDS u16 gathers are 2-way (free).
    int fl = tid & 127, hf = tid >> 7;
    size_t base = ((size_t)((b * 8 + ft) * 16) + (t0 >> 5) + hf) * 4096;
#pragma unroll
    for (int qq = 0; qq < 4; ++qq) {
        int tr = hf * 32 + qq * 8;
        uint32_t w0 = (uint32_t)tile[(tr + 0) * 128 + fl] | ((uint32_t)tile[(tr + 1) * 128 + fl] << 16);
        uint32_t w1 = (uint32_t)tile[(tr + 2) * 128 + fl] | ((uint32_t)tile[(tr + 3) * 128 + fl] << 16);
        uint32_t w2 = (uint32_t)tile[(tr + 4) * 128 + fl] | ((uint32_t)tile[(tr + 5) * 128 + fl] << 16);
        uint32_t w3 = (uint32_t)tile[(tr + 6) * 128 + fl] | ((uint32_t)tile[(tr + 7) * 128 + fl] << 16);
        uint4 o = make_uint4(w0, w1, w2, w3);
        *(uint4*)&xTC[base + (size_t)(qq * 128 + fl) * 8] = o;
    }
}

// ---------------------------------------------------------------------------
// Kernel 2: cast W to bf16 in CHUNKED layout + per-row sum.
// ---------------------------------------------------------------------------
__global__ __launch_bounds__(256) void k_wcast(
    const float* __restrict__ W, ushort_t* __restrict__ WbC,
    float* __restrict__ rowsumW)
{
    __shared__ float red[4];
    int u = blockIdx.x, tid = threadIdx.x;
    float2 lv = *(const float2*)(W + (size_t)u * 512 + 2 * tid);

    int mt = u >> 7, m = u & 127;
    int kt = tid >> 4;
    int qq = (tid & 15) >> 2;
    int e  = 2 * (tid & 3);
    size_t off = ((size_t)(mt * 16 + kt)) * 4096 + (size_t)(qq * 128 + m) * 8 + e;
    uint32_t pk = (uint32_t)f2bf(lv.x) | ((uint32_t)f2bf(lv.y) << 16);
    *(uint32_t*)&WbC[off] = pk;

    float s = lv.x + lv.y;
#pragma unroll
    for (int off2 = 32; off2 > 0; off2 >>= 1) s += __shfl_down(s, off2, 64);
    int lane = tid & 63, w = tid >> 6;
    if (lane == 0) red[w] = s;
    __syncthreads();
    if (tid == 0) rowsumW[u] = red[0] + red[1] + red[2] + red[3];
}

// ---------------------------------------------------------------------------
// Kernel 3: single-block final reduce: partials -> a; d[u] = c*rowsumW + bias.
// ---------------------------------------------------------------------------
__global__ __launch_bounds__(256) void k_reduce(
    const float2* __restrict__ partials, const float* __restrict__ rowsumW,
    const float* __restrict__ bias, const float* __restrict__ gamma,
    const float* __restrict__ beta, float* __restrict__ stats,
    float* __restrict__ d)
{
    __shared__ float red[8];
    __shared__ float sac[2];
    int tid = threadIdx.x;
    float s = 0.f, q = 0.f;
#pragma unroll
    for (int i = 0; i < 16; ++i) {
        float2 p = partials[i * 256 + tid];
        s += p.x; q += p.y;
    }
#pragma unroll
    for (int off = 32; off > 0; off >>= 1) {
        s += __shfl_down(s, off, 64);
        q += __shfl_down(q, off, 64);
    }
    int lane = tid & 63, w = tid >> 6;
    if (lane == 0) { red[w] = s; red[4 + w] = q; }
    __syncthreads();
    if (tid == 0) {
        float S = red[0] + red[1] + red[2] + red[3];
        float Q = red[4] + red[5] + red[6] + red[7];
        float mean = S * (1.f / NTOT);
        float var  = Q * (1.f / NTOT) - mean * mean;
        float a    = gamma[0] * rsqrtf(var + EPS);
        float c    = beta[0] - mean * a;
        stats[0] = a;
        sac[0] = a; sac[1] = c;
    }
    __syncthreads();
    float c = sac[1];
    d[tid]       = c * rowsumW[tid]       + bias[tid];
    d[tid + 256] = c * rowsumW[tid + 256] + bias[tid + 256];
}

// ---------------------------------------------------------------------------
// Kernel 4: GEMM, chunked operands -> perfectly coalesced global_load_lds
// (1KB contiguous per wave-instruction). 128x128 tile, BK=32, 16x16x32 MFMA.
// Epilogue routes C through LDS: float4-coalesced residual read + store.
// ---------------------------------------------------------------------------
__global__ __launch_bounds__(256) void k_gemm(
    const ushort_t* __restrict__ WbC, const ushort_t* __restrict__ xTC,
    const float* __restrict__ x, const float* __restrict__ d,
    const float* __restrict__ stats, float* __restrict__ out)
{
    __shared__ ulong smem_raw[2176];             // 17408 B, aliased
    ushort_t* ldsA = (ushort_t*)smem_raw;        // 8KB
    ushort_t* ldsB = ldsA + 4096;                // 8KB
    float*    ldsC = (float*)smem_raw;           // 32*132*4 = 16896 B (epilogue)

    int tid = threadIdx.x;
    int w = tid >> 6, lane = tid & 63;
    int mt = blockIdx.x;             // 0..3   (t tile)
    int nt = blockIdx.y;             // 0..511 (b, f tile)
    int b = nt >> 3, ft = nt & 7;
    int wr = w >> 1, wc = w & 1;
    int l15 = lane & 15, q = lane >> 4;

    const ushort_t* Abase = WbC + (size_t)mt * 16 * 4096;
    const ushort_t* Bbase = xTC + (size_t)(b * 8 + ft) * 16 * 4096;

    floatx4 acc[4][4] = {};

    for (int kt = 0; kt < 16; ++kt) {
        const ushort_t* Ag = Abase + kt * 4096 + tid * 8;
        const ushort_t* Bg = Bbase + kt * 4096 + tid * 8;
        async16(Ag,        &ldsA[tid * 8]);
        async16(Ag + 2048, &ldsA[2048 + tid * 8]);
        async16(Bg,        &ldsB[tid * 8]);
        async16(Bg + 2048, &ldsB[2048 + tid * 8]);
        __syncthreads();

        short8 af[4], bfr[4];
#pragma unroll
        for (int i = 0; i < 4; ++i) {
            int m = wr * 64 + i * 16 + l15;
            af[i] = *(const short8*)&ldsA[(q * 128 + m) * 8];
        }
#pragma unroll
        for (int j = 0; j < 4; ++j) {
            int n = wc * 64 + j * 16 + l15;
            bfr[j] = *(const short8*)&ldsB[(q * 128 + n) * 8];
        }
#pragma unroll
        for (int i = 0; i < 4; ++i)
#pragma unroll
            for (int j = 0; j < 4; ++j)
                acc[i][j] = __builtin_amdgcn_mfma_f32_16x16x32_bf16(
                    af[i], bfr[j], acc[i][j], 0, 0, 0);
        __syncthreads();
    }

    // epilogue: 4 passes of 32 rows through LDS (stride 132 -> 2-way only)
    float a = stats[0];
    int row = tid >> 3, cs = (tid & 7) * 16;
#pragma unroll
    for (int p = 0; p < 4; ++p) {
        if (wr == (p >> 1)) {
#pragma unroll
            for (int ii = 0; ii < 2; ++ii) {
                int i = (p & 1) * 2 + ii;
                int rl0 = i * 16 + q * 4 - (p & 1) * 32;
#pragma unroll
                for (int j = 0; j < 4; ++j) {
                    int col = wc * 64 + j * 16 + l15;
#pragma unroll
                    for (int r = 0; r < 4; ++r)
                        ldsC[(rl0 + r) * 132 + col] = acc[i][j][r];
                }
            }
        }
        __syncthreads();
        int tg = mt * 128 + p * 32 + row;
        float dt = d[tg];
        size_t gbase = ((size_t)b * TDIM + tg) * FDIM + ft * 128 + cs;
        const float* xr = x + gbase;
        float* orow = out + gbase;
#pragma unroll
        for (int k4 = 0; k4 < 4; ++k4) {
            float4 xv = *(const float4*)(xr + k4 * 4);
            float4 cv = *(const float4*)&ldsC[row * 132 + cs + k4 * 4];
            float4 o;
            o.x = xv.x + fmaxf(a * cv.x + dt, 0.f);
            o.y = xv.y + fmaxf(a * cv.y + dt, 0.f);
            o.z = xv.z + fmaxf(a * cv.z + dt, 0.f);
            o.w = xv.w + fmaxf(a * cv.w + dt, 0.f);
            *(float4*)(orow + k4 * 4) = o;
        }
        __syncthreads();
    }
}

// ---------------------------------------------------------------------------
extern "C" void kernel_launch(void* const* d_in, const int* in_sizes, int n_in,
                              void* d_out, int out_size, void* d_ws, size_t ws_size,
                              hipStream_t stream) {
    const float* x     = (const float*)d_in[0];
    const float* W     = (const float*)d_in[1];
    const float* bias  = (const float*)d_in[2];
    const float* gamma = (const float*)d_in[3];
    const float* beta  = (const float*)d_in[4];
    float* out = (float*)d_out;

    char* ws = (char*)d_ws;
    float*    stats    = (float*)ws;                   // 8 B
    float*    dvec     = (float*)(ws + 1024);          // 2 KB
    float*    rowsumW  = (float*)(ws + 4096);          // 2 KB
    float2*   partials = (float2*)(ws + 8192);         // 32 KB
    ushort_t* WbC      = (ushort_t*)(ws + (64 << 10)); // 512 KB
    ushort_t* xTC      = (ushort_t*)(ws + (1 << 20));  // 64 MB

    k_stats_transpose<<<4096, 256, 0, stream>>>(x, xTC, partials);
    k_wcast<<<512, 256, 0, stream>>>(W, WbC, rowsumW);
    k_reduce<<<1, 256, 0, stream>>>(partials, rowsumW, bias, gamma, beta, stats, dvec);
    k_gemm<<<dim3(4, 512), 256, 0, stream>>>(WbC, xTC, x, dvec, stats, out);
}